// Round 6
// baseline (143.276 us; speedup 1.0000x reference)
//
#include <hip/hip_runtime.h>
#include <hip/hip_bf16.h>

#define LRELU_ALPHA 0.2f

constexpr int N   = 8192;
constexpr int FIN = 512;
constexpr int F   = 128;
constexpr int BRW = 16;          // rows per wave
constexpr int BR  = 64;          // rows per block (4 waves)
constexpr int BK  = 64;          // j per LDS tile (2 MFMA k-steps)
constexpr int NW64 = N / 64;     // u64s per mask row

typedef __attribute__((ext_vector_type(4))) float f32x4;
typedef __attribute__((ext_vector_type(8))) short s16x8;
typedef __attribute__((ext_vector_type(4))) short s16x4;
typedef __attribute__((ext_vector_type(4))) int   i32x4;
typedef unsigned long long u64;

static __device__ __forceinline__ short f2bf(float x) {
  unsigned u = __float_as_uint(x);
  return (short)((u + 0x7fffu + ((u >> 16) & 1u)) >> 16);   // RNE bf16
}

// ---------------------------------------------------------------------------
// K0: compress adj (int32 0/1, 268 MB) -> bitmask (8 MB). Pure stream.
// One wave per row; lane l reads adj[row][j0+l]; __ballot gives the u64
// in exact j-order (bit l = lane l). 8 independent loads in flight/iter.
// ---------------------------------------------------------------------------
__global__ __launch_bounds__(256) void k_mask(
    const int* __restrict__ adj, u64* __restrict__ mask) {
  const int l   = threadIdx.x & 63;
  const int row = blockIdx.x * 4 + (threadIdx.x >> 6);
  const int* __restrict__ rp = adj + (size_t)row * N;
  u64* __restrict__ mp = mask + (size_t)row * NW64;
  for (int it = 0; it < N / 512; ++it) {        // 16 iters x 512 j
    const int base = it * 512 + l;
    int v[8];
#pragma unroll
    for (int k = 0; k < 8; ++k) v[k] = rp[base + k * 64];
    u64 m[8];
#pragma unroll
    for (int k = 0; k < 8; ++k) m[k] = __ballot(v[k] > 0);
    if (l == 0) {
      ulonglong2 s0 = {m[0], m[1]}, s1 = {m[2], m[3]};
      ulonglong2 s2 = {m[4], m[5]}, s3 = {m[6], m[7]};
      *(ulonglong2*)(mp + it * 8)     = s0;
      *(ulonglong2*)(mp + it * 8 + 2) = s1;
      *(ulonglong2*)(mp + it * 8 + 4) = s2;
      *(ulonglong2*)(mp + it * 8 + 6) = s3;
    }
  }
}

// ---------------------------------------------------------------------------
// K1: WhbT = (h@w)^T bf16 [F][N]; Wh1 = Wh@a[:128]; Wh2 = Wh@a[128:] (f32).
// ---------------------------------------------------------------------------
__global__ __launch_bounds__(256) void k_wh(
    const float* __restrict__ h, const float* __restrict__ w,
    const float* __restrict__ a, __hip_bfloat16* __restrict__ WhbT,
    float* __restrict__ Wh1, float* __restrict__ Wh2) {
  __shared__ float hl[32][68];
  __shared__ float wl[64][128];
  const int t    = threadIdx.x;
  const int i0   = blockIdx.x * 32;
  const int col4 = (t & 31) * 4;
  const int rq   = t >> 5;
  float acc[4][4] = {};

  for (int k0 = 0; k0 < FIN; k0 += 64) {
#pragma unroll
    for (int j = 0; j < 2; ++j) {
      int c = t + 256 * j;
      int r = c >> 4, kq = c & 15;
      *(f32x4*)&hl[r][kq * 4] =
          *(const f32x4*)(h + (size_t)(i0 + r) * FIN + k0 + kq * 4);
    }
#pragma unroll
    for (int j = 0; j < 8; ++j) {
      int c = t + 256 * j;
      int kr = c >> 5, f4 = (c & 31) * 4;
      *(f32x4*)&wl[kr][f4] = *(const f32x4*)(w + (size_t)(k0 + kr) * F + f4);
    }
    __syncthreads();
#pragma unroll 4
    for (int k4 = 0; k4 < 64; k4 += 4) {
      f32x4 wv[4];
#pragma unroll
      for (int u = 0; u < 4; ++u) wv[u] = *(const f32x4*)&wl[k4 + u][col4];
#pragma unroll
      for (int ri = 0; ri < 4; ++ri) {
        f32x4 hv = *(const f32x4*)&hl[rq * 4 + ri][k4];
#pragma unroll
        for (int u = 0; u < 4; ++u) {
#pragma unroll
          for (int ci = 0; ci < 4; ++ci) acc[ri][ci] += hv[u] * wv[u][ci];
        }
      }
    }
    __syncthreads();
  }
#pragma unroll
  for (int ci = 0; ci < 4; ++ci) {
    int f = col4 + ci;
    s16x4 o = {f2bf(acc[0][ci]), f2bf(acc[1][ci]),
               f2bf(acc[2][ci]), f2bf(acc[3][ci])};
    *(s16x4*)((short*)WhbT + (size_t)f * N + i0 + rq * 4) = o;
  }
  f32x4 av1 = *(const f32x4*)(a + col4);
  f32x4 av2 = *(const f32x4*)(a + F + col4);
  float s1[4], s2[4];
#pragma unroll
  for (int ri = 0; ri < 4; ++ri) {
    s1[ri] = acc[ri][0] * av1[0] + acc[ri][1] * av1[1] +
             acc[ri][2] * av1[2] + acc[ri][3] * av1[3];
    s2[ri] = acc[ri][0] * av2[0] + acc[ri][1] * av2[1] +
             acc[ri][2] * av2[2] + acc[ri][3] * av2[3];
  }
#pragma unroll
  for (int off = 1; off < 32; off <<= 1) {
#pragma unroll
    for (int ri = 0; ri < 4; ++ri) {
      s1[ri] += __shfl_xor(s1[ri], off);
      s2[ri] += __shfl_xor(s2[ri], off);
    }
  }
  if ((t & 31) == 0) {
#pragma unroll
    for (int ri = 0; ri < 4; ++ri) {
      Wh1[i0 + rq * 4 + ri] = s1[ri];
      Wh2[i0 + rq * 4 + ri] = s2[ri];
    }
  }
}

// ---------------------------------------------------------------------------
// K2: fused GAT attention partials, LDS-pipelined, bitmask adjacency.
// grid (128, KS), block 256 = 4 waves; block = 64 rows x 128 cols x JW j.
// Per BK=64 j-tile: B-tile staged into double-buffered XOR-swizzled LDS;
// adjacency is ONE broadcast u64 per row per tile (L2-resident mask);
// Wh2 JIT (L1). Scores bounded -> p = bit ? exp(lrelu(Wh1+Wh2)) : 0.
// One barrier per tile.
// ---------------------------------------------------------------------------
template <int KS>
__global__ __launch_bounds__(256) __attribute__((amdgpu_waves_per_eu(1, 4)))
void k_attn(
    const u64* __restrict__ mask, const float* __restrict__ Wh1v,
    const float* __restrict__ Wh2v, const __hip_bfloat16* __restrict__ WhbT,
    float* __restrict__ accP, float* __restrict__ lP) {
  constexpr int JW  = N / KS;
  constexpr int NTL = JW / BK;     // 16 for KS=8 (even)
  __shared__ __align__(16) short Bl[2][F * BK];   // 2 x 16 KB

  const int t   = threadIdx.x;
  const int l   = t & 63;
  const int w   = t >> 6;
  const int r16 = l & 15;
  const int g8  = (l >> 4) * 8;
  const int i0  = blockIdx.x * BR;
  const int s   = blockIdx.y;

  const int row  = i0 + w * BRW + r16;
  const float w1 = Wh1v[row];
  const u64* __restrict__ mrow   = mask + (size_t)row * NW64 + s * (JW / 64);
  const float* __restrict__ w2p  = Wh2v + (size_t)s * JW;
  const short* __restrict__ bsrc = (const short*)WhbT + (size_t)s * JW;

  // staging map: chunk c = t + 256*q (16 B each); row fr = c>>3, gran = c&7
  int ldsoff[4]; size_t goff[4];
#pragma unroll
  for (int q = 0; q < 4; ++q) {
    int c  = t + 256 * q;
    int fr = c >> 3;
    ldsoff[q] = (c * 16) ^ ((fr & 7) << 4);           // swizzled LDS byte
    goff[q]   = (size_t)fr * N + (c & 7) * 8;         // linear global (shorts)
  }
  const int sw = (r16 & 7) << 4;                       // read-side XOR

  f32x4 acc[8] = {};
  float lsum = 0.f;
  s16x8 sv[4];

  // score operands for one tile, in registers
  u64 mA, mB;
  f32x4 cA0, cA1, cA2, cA3, cB0, cB1, cB2, cB3;

#define LOAD_SCORE(M, C0, C1, C2, C3, tile)                                  \
  M  = mrow[(tile)];                                                         \
  C0 = *(const f32x4*)(w2p + (tile) * BK + g8);                              \
  C1 = *(const f32x4*)(w2p + (tile) * BK + g8 + 4);                          \
  C2 = *(const f32x4*)(w2p + (tile) * BK + g8 + 32);                         \
  C3 = *(const f32x4*)(w2p + (tile) * BK + g8 + 36);

  auto scores = [&](u64 m, const f32x4& y0, const f32x4& y1,
                    const f32x4& y2, const f32x4& y3, s16x8& af0, s16x8& af1) {
    const unsigned b0 = (unsigned)(m >> g8) & 0xffu;          // jj g8..g8+7
    const unsigned b1 = (unsigned)(m >> (g8 + 32)) & 0xffu;   // jj g8+32..+39
    float p[16];
#pragma unroll
    for (int u = 0; u < 4; ++u) {
      float x = w1 + y0[u]; x = fmaxf(x, LRELU_ALPHA * x);
      p[u] = (b0 >> u) & 1u ? __expf(x) : 0.f;
    }
#pragma unroll
    for (int u = 0; u < 4; ++u) {
      float x = w1 + y1[u]; x = fmaxf(x, LRELU_ALPHA * x);
      p[4 + u] = (b0 >> (4 + u)) & 1u ? __expf(x) : 0.f;
    }
#pragma unroll
    for (int u = 0; u < 4; ++u) {
      float x = w1 + y2[u]; x = fmaxf(x, LRELU_ALPHA * x);
      p[8 + u] = (b1 >> u) & 1u ? __expf(x) : 0.f;
    }
#pragma unroll
    for (int u = 0; u < 4; ++u) {
      float x = w1 + y3[u]; x = fmaxf(x, LRELU_ALPHA * x);
      p[12 + u] = (b1 >> (4 + u)) & 1u ? __expf(x) : 0.f;
    }
#pragma unroll
    for (int u = 0; u < 16; ++u) lsum += p[u];
    af0 = s16x8{f2bf(p[0]),  f2bf(p[1]),  f2bf(p[2]),  f2bf(p[3]),
                f2bf(p[4]),  f2bf(p[5]),  f2bf(p[6]),  f2bf(p[7])};
    af1 = s16x8{f2bf(p[8]),  f2bf(p[9]),  f2bf(p[10]), f2bf(p[11]),
                f2bf(p[12]), f2bf(p[13]), f2bf(p[14]), f2bf(p[15])};
  };

  auto mfma_tile = [&](const char* pb, s16x8 af0, s16x8 af1) {
#pragma unroll
    for (int nb = 0; nb < 8; ++nb) {
      const int rbase = (nb * 16 + r16) * 128;
      s16x8 b0 = *(const s16x8*)(pb + rbase + ((g8 * 2) ^ sw));
      s16x8 b1 = *(const s16x8*)(pb + rbase + ((g8 * 2 + 64) ^ sw));
      acc[nb] = __builtin_amdgcn_mfma_f32_16x16x32_bf16(af0, b0, acc[nb], 0, 0, 0);
      acc[nb] = __builtin_amdgcn_mfma_f32_16x16x32_bf16(af1, b1, acc[nb], 0, 0, 0);
    }
  };

  // ---- prologue: stage tile 0 -> buf0; score-regs for tiles 0,1 ----
#pragma unroll
  for (int q = 0; q < 4; ++q) sv[q] = *(const s16x8*)(bsrc + goff[q]);
  LOAD_SCORE(mA, cA0, cA1, cA2, cA3, 0)
  LOAD_SCORE(mB, cB0, cB1, cB2, cB3, 1)
#pragma unroll
  for (int q = 0; q < 4; ++q)
    *(s16x8*)((char*)&Bl[0][0] + ldsoff[q]) = sv[q];
  __syncthreads();

  for (int tl = 0; tl < NTL; tl += 2) {
    // ======== even tile tl: read buf0, stage tl+1 -> buf1, refill A ========
    {
      const size_t tn = (size_t)(tl + 1 < NTL ? tl + 1 : NTL - 1) * BK;
#pragma unroll
      for (int q = 0; q < 4; ++q)
        sv[q] = *(const s16x8*)(bsrc + goff[q] + tn);
    }
    {
      s16x8 af0, af1;
      scores(mA, cA0, cA1, cA2, cA3, af0, af1);
      const int tp = (tl + 2 < NTL ? tl + 2 : tl);   // clamp: dup unused
      LOAD_SCORE(mA, cA0, cA1, cA2, cA3, tp)
#pragma unroll
      for (int q = 0; q < 4; ++q)
        *(s16x8*)((char*)&Bl[1][0] + ldsoff[q]) = sv[q];
      mfma_tile((const char*)&Bl[0][0], af0, af1);
    }
    __syncthreads();
    // ======== odd tile tl+1: read buf1, stage tl+2 -> buf0, refill B ========
    {
      const size_t tn = (size_t)(tl + 2 < NTL ? tl + 2 : NTL - 1) * BK;
#pragma unroll
      for (int q = 0; q < 4; ++q)
        sv[q] = *(const s16x8*)(bsrc + goff[q] + tn);
    }
    {
      s16x8 af0, af1;
      scores(mB, cB0, cB1, cB2, cB3, af0, af1);
      const int tp = (tl + 3 < NTL ? tl + 3 : tl + 1);
      LOAD_SCORE(mB, cB0, cB1, cB2, cB3, tp)
#pragma unroll
      for (int q = 0; q < 4; ++q)
        *(s16x8*)((char*)&Bl[0][0] + ldsoff[q]) = sv[q];
      mfma_tile((const char*)&Bl[1][0], af0, af1);
    }
    __syncthreads();
  }
#undef LOAD_SCORE

  // row-sums: lanes {l, l^16, l^32, l^48} hold the row's k-slot partials
  lsum += __shfl_xor(lsum, 16);
  lsum += __shfl_xor(lsum, 32);
  if (l < 16) lP[(size_t)s * N + row] = lsum;
  // partial accumulator (C layout: row=(l>>4)*4+rg, col=l&15)
  float* op = accP + (size_t)s * N * F;
#pragma unroll
  for (int nb = 0; nb < 8; ++nb) {
#pragma unroll
    for (int rg = 0; rg < 4; ++rg) {
      int r = i0 + w * BRW + (l >> 4) * 4 + rg;
      op[(size_t)r * F + nb * 16 + r16] = acc[nb][rg];
    }
  }
}

// ---------------------------------------------------------------------------
// K3: combine partials: out = elu( (sum_s accP) / (sum_s lP) )
// ---------------------------------------------------------------------------
template <int KS>
__global__ __launch_bounds__(256) void k_comb(
    const float* __restrict__ accP, const float* __restrict__ lP,
    float* __restrict__ out) {
  const int idx = blockIdx.x * 256 + threadIdx.x;  // one f32x4 per thread
  const int i   = idx >> 5;                        // row (F/4 = 32 per row)
  f32x4 v = {};
  float lt = 0.f;
#pragma unroll
  for (int s = 0; s < KS; ++s) {
    v += *(const f32x4*)(accP + (size_t)s * N * F + (size_t)idx * 4);
    lt += lP[(size_t)s * N + i];
  }
  f32x4 o;
#pragma unroll
  for (int u = 0; u < 4; ++u) {
    float x = v[u] / lt;
    o[u] = x > 0.f ? x : __expf(x) - 1.f;          // ELU
  }
  *(f32x4*)(out + (size_t)idx * 4) = o;
}

// ---------------------------------------------------------------------------
extern "C" void kernel_launch(void* const* d_in, const int* in_sizes, int n_in,
                              void* d_out, int out_size, void* d_ws, size_t ws_size,
                              hipStream_t stream) {
  const float* h   = (const float*)d_in[0];
  const int*   adj = (const int*)d_in[1];
  const float* w   = (const float*)d_in[2];
  const float* a   = (const float*)d_in[3];
  float* out = (float*)d_out;

  // ws: WhbT bf16 [F][N] | Wh1 [N] | Wh2 [N] | mask [N][N/64] u64 (8 MB)
  //     | lP [KS][N] | accP [KS][N][F]
  char* ws = (char*)d_ws;
  __hip_bfloat16* WhbT = (__hip_bfloat16*)ws;
  float* Wh1 = (float*)(ws + (size_t)F * N * 2);
  float* Wh2 = Wh1 + N;
  u64*  mask = (u64*)(Wh2 + N);
  float* lP  = (float*)(mask + (size_t)N * NW64);

  const size_t fixed = (size_t)F * N * 2 + 2 * (size_t)N * 4 +
                       (size_t)N * NW64 * 8;
  const size_t need8 = fixed + 8 * (size_t)N * 4 + 8 * (size_t)N * F * 4;

  k_mask<<<N / 4, 256, 0, stream>>>(adj, mask);
  k_wh<<<N / 32, 256, 0, stream>>>(h, w, a, WhbT, Wh1, Wh2);
  if (ws_size >= need8) {
    constexpr int KS = 8;
    float* accP = lP + (size_t)KS * N;
    k_attn<KS><<<dim3(N / BR, KS), 256, 0, stream>>>(mask, Wh1, Wh2, WhbT,
                                                     accP, lP);
    k_comb<KS><<<(N * F / 4) / 256, 256, 0, stream>>>(accP, lP, out);
  } else {
    constexpr int KS = 4;
    float* accP = lP + (size_t)KS * N;
    k_attn<KS><<<dim3(N / BR, KS), 256, 0, stream>>>(mask, Wh1, Wh2, WhbT,
                                                     accP, lP);
    k_comb<KS><<<(N * F / 4) / 256, 256, 0, stream>>>(accP, lP, out);
  }
}

// Round 7
// 132.935 us; speedup vs baseline: 1.0778x; 1.0778x over previous
//
#include <hip/hip_runtime.h>
#include <hip/hip_bf16.h>

#define LRELU_ALPHA 0.2f

constexpr int N   = 8192;
constexpr int FIN = 512;
constexpr int F   = 128;
constexpr int BRW = 16;          // rows per wave
constexpr int BR  = 64;          // rows per block (4 waves)
constexpr int BK  = 64;          // j per LDS tile (2 MFMA k-steps)

typedef __attribute__((ext_vector_type(4))) float f32x4;
typedef __attribute__((ext_vector_type(8))) short s16x8;
typedef __attribute__((ext_vector_type(4))) short s16x4;
typedef __attribute__((ext_vector_type(4))) int   i32x4;
typedef unsigned long long u64;

static __device__ __forceinline__ short f2bf(float x) {
  unsigned u = __float_as_uint(x);
  return (short)((u + 0x7fffu + ((u >> 16) & 1u)) >> 16);   // RNE bf16
}

// ---------------------------------------------------------------------------
// K1: WhbT = (h@w)^T bf16 [F][N]; Wh1 = Wh@a[:128]; Wh2 = Wh@a[128:] (f32).
// ---------------------------------------------------------------------------
__global__ __launch_bounds__(256) void k_wh(
    const float* __restrict__ h, const float* __restrict__ w,
    const float* __restrict__ a, __hip_bfloat16* __restrict__ WhbT,
    float* __restrict__ Wh1, float* __restrict__ Wh2) {
  __shared__ float hl[32][68];
  __shared__ float wl[64][128];
  const int t    = threadIdx.x;
  const int i0   = blockIdx.x * 32;
  const int col4 = (t & 31) * 4;
  const int rq   = t >> 5;
  float acc[4][4] = {};

  for (int k0 = 0; k0 < FIN; k0 += 64) {
#pragma unroll
    for (int j = 0; j < 2; ++j) {
      int c = t + 256 * j;
      int r = c >> 4, kq = c & 15;
      *(f32x4*)&hl[r][kq * 4] =
          *(const f32x4*)(h + (size_t)(i0 + r) * FIN + k0 + kq * 4);
    }
#pragma unroll
    for (int j = 0; j < 8; ++j) {
      int c = t + 256 * j;
      int kr = c >> 5, f4 = (c & 31) * 4;
      *(f32x4*)&wl[kr][f4] = *(const f32x4*)(w + (size_t)(k0 + kr) * F + f4);
    }
    __syncthreads();
#pragma unroll 4
    for (int k4 = 0; k4 < 64; k4 += 4) {
      f32x4 wv[4];
#pragma unroll
      for (int u = 0; u < 4; ++u) wv[u] = *(const f32x4*)&wl[k4 + u][col4];
#pragma unroll
      for (int ri = 0; ri < 4; ++ri) {
        f32x4 hv = *(const f32x4*)&hl[rq * 4 + ri][k4];
#pragma unroll
        for (int u = 0; u < 4; ++u) {
#pragma unroll
          for (int ci = 0; ci < 4; ++ci) acc[ri][ci] += hv[u] * wv[u][ci];
        }
      }
    }
    __syncthreads();
  }
#pragma unroll
  for (int ci = 0; ci < 4; ++ci) {
    int f = col4 + ci;
    s16x4 o = {f2bf(acc[0][ci]), f2bf(acc[1][ci]),
               f2bf(acc[2][ci]), f2bf(acc[3][ci])};
    *(s16x4*)((short*)WhbT + (size_t)f * N + i0 + rq * 4) = o;
  }
  f32x4 av1 = *(const f32x4*)(a + col4);
  f32x4 av2 = *(const f32x4*)(a + F + col4);
  float s1[4], s2[4];
#pragma unroll
  for (int ri = 0; ri < 4; ++ri) {
    s1[ri] = acc[ri][0] * av1[0] + acc[ri][1] * av1[1] +
             acc[ri][2] * av1[2] + acc[ri][3] * av1[3];
    s2[ri] = acc[ri][0] * av2[0] + acc[ri][1] * av2[1] +
             acc[ri][2] * av2[2] + acc[ri][3] * av2[3];
  }
#pragma unroll
  for (int off = 1; off < 32; off <<= 1) {
#pragma unroll
    for (int ri = 0; ri < 4; ++ri) {
      s1[ri] += __shfl_xor(s1[ri], off);
      s2[ri] += __shfl_xor(s2[ri], off);
    }
  }
  if ((t & 31) == 0) {
#pragma unroll
    for (int ri = 0; ri < 4; ++ri) {
      Wh1[i0 + rq * 4 + ri] = s1[ri];
      Wh2[i0 + rq * 4 + ri] = s2[ri];
    }
  }
}

// ---------------------------------------------------------------------------
// K2: fused GAT attention partials.
// Phase 1 (barrier-free): stream this block's 64-row x JW adj window,
// ballot-compress to an LDS bitmask (8 KB, column-XOR-swizzled); copy the
// Wh2 window (4 KB) to LDS. Pure coalesced streaming at HBM rate; overlaps
// other resident blocks' phase 2.
// Phase 2: per BK=64 tile: stage B-tile into double-buffered XOR-swizzled
// LDS (only vmcnt traffic, L2); scores read mask+Wh2 from LDS (lgkm only);
// MFMA 16x16x32. One barrier per tile.
// ---------------------------------------------------------------------------
template <int KS>
__global__ __launch_bounds__(256) __attribute__((amdgpu_waves_per_eu(1, 4)))
void k_attn(
    const int* __restrict__ adj, const float* __restrict__ Wh1v,
    const float* __restrict__ Wh2v, const __hip_bfloat16* __restrict__ WhbT,
    float* __restrict__ accP, float* __restrict__ lP) {
  constexpr int JW  = N / KS;
  constexpr int NTL = JW / BK;     // 16 for KS=8 (even)
  __shared__ __align__(16) short Bl[2][F * BK];   // 2 x 16 KB
  __shared__ u64   ml[BR][NTL];                    // bitmask, col ^ (row&15)
  __shared__ float w2l[JW];

  const int t   = threadIdx.x;
  const int l   = t & 63;
  const int w   = t >> 6;
  const int r16 = l & 15;
  const int g8  = (l >> 4) * 8;
  const int i0  = blockIdx.x * BR;
  const int s   = blockIdx.y;

  const int row  = i0 + w * BRW + r16;
  const float w1 = Wh1v[row];
  const float* __restrict__ w2p  = Wh2v + (size_t)s * JW;
  const short* __restrict__ bsrc = (const short*)WhbT + (size_t)s * JW;

  // staging map: chunk c = t + 256*q (16 B each); row fr = c>>3
  int ldsoff[4]; size_t goff[4];
#pragma unroll
  for (int q = 0; q < 4; ++q) {
    int c  = t + 256 * q;
    int fr = c >> 3;
    ldsoff[q] = (c * 16) ^ ((fr & 7) << 4);           // swizzled LDS byte
    goff[q]   = (size_t)fr * N + (c & 7) * 8;         // linear global (shorts)
  }
  const int sw = (r16 & 7) << 4;                       // read-side XOR

  f32x4 acc[8] = {};
  float lsum = 0.f;
  s16x8 sv[4];

  // ---- issue stage loads for tile 0 (L2; land during phase 1) ----
#pragma unroll
  for (int q = 0; q < 4; ++q) sv[q] = *(const s16x8*)(bsrc + goff[q]);

  // ---- phase 1a: Wh2 window -> LDS ----
  if (t * 4 < JW) *(f32x4*)&w2l[t * 4] = *(const f32x4*)(w2p + t * 4);

  // ---- phase 1b: adj window -> LDS bitmask (wave w: rows w*16..w*16+15) ----
  {
    const int* __restrict__ ap = adj + (size_t)(i0 + w * BRW) * N +
                                 (size_t)s * JW;
    for (int r = 0; r < BRW; ++r) {
      const int* __restrict__ rp = ap + (size_t)r * N;
#pragma unroll
      for (int it = 0; it < JW / 512; ++it) {
        int v[8];
#pragma unroll
        for (int k = 0; k < 8; ++k) v[k] = rp[it * 512 + l + k * 64];
        u64 m[8];
#pragma unroll
        for (int k = 0; k < 8; ++k) m[k] = __ballot(v[k] > 0);
        if (l == 0) {
#pragma unroll
          for (int k = 0; k < 8; ++k)
            ml[w * BRW + r][(it * 8 + k) ^ r] = m[k];
        }
      }
    }
  }
  // ---- commit tile-0 B stage + all LDS, single barrier ----
#pragma unroll
  for (int q = 0; q < 4; ++q)
    *(s16x8*)((char*)&Bl[0][0] + ldsoff[q]) = sv[q];
  __syncthreads();

  auto scores = [&](int tl, s16x8& af0, s16x8& af1) {
    const u64 m = ml[w * BRW + r16][tl ^ r16];
    const f32x4 y0 = *(const f32x4*)&w2l[tl * BK + g8];
    const f32x4 y1 = *(const f32x4*)&w2l[tl * BK + g8 + 4];
    const f32x4 y2 = *(const f32x4*)&w2l[tl * BK + g8 + 32];
    const f32x4 y3 = *(const f32x4*)&w2l[tl * BK + g8 + 36];
    const unsigned b0 = (unsigned)(m >> g8) & 0xffu;
    const unsigned b1 = (unsigned)(m >> (g8 + 32)) & 0xffu;
    float p[16];
#pragma unroll
    for (int u = 0; u < 4; ++u) {
      float x = w1 + y0[u]; x = fmaxf(x, LRELU_ALPHA * x);
      p[u] = (b0 >> u) & 1u ? __expf(x) : 0.f;
    }
#pragma unroll
    for (int u = 0; u < 4; ++u) {
      float x = w1 + y1[u]; x = fmaxf(x, LRELU_ALPHA * x);
      p[4 + u] = (b0 >> (4 + u)) & 1u ? __expf(x) : 0.f;
    }
#pragma unroll
    for (int u = 0; u < 4; ++u) {
      float x = w1 + y2[u]; x = fmaxf(x, LRELU_ALPHA * x);
      p[8 + u] = (b1 >> u) & 1u ? __expf(x) : 0.f;
    }
#pragma unroll
    for (int u = 0; u < 4; ++u) {
      float x = w1 + y3[u]; x = fmaxf(x, LRELU_ALPHA * x);
      p[12 + u] = (b1 >> (4 + u)) & 1u ? __expf(x) : 0.f;
    }
#pragma unroll
    for (int u = 0; u < 16; ++u) lsum += p[u];
    af0 = s16x8{f2bf(p[0]),  f2bf(p[1]),  f2bf(p[2]),  f2bf(p[3]),
                f2bf(p[4]),  f2bf(p[5]),  f2bf(p[6]),  f2bf(p[7])};
    af1 = s16x8{f2bf(p[8]),  f2bf(p[9]),  f2bf(p[10]), f2bf(p[11]),
                f2bf(p[12]), f2bf(p[13]), f2bf(p[14]), f2bf(p[15])};
  };

  auto mfma_tile = [&](const char* pb, s16x8 af0, s16x8 af1) {
#pragma unroll
    for (int nb = 0; nb < 8; ++nb) {
      const int rbase = (nb * 16 + r16) * 128;
      s16x8 b0 = *(const s16x8*)(pb + rbase + ((g8 * 2) ^ sw));
      s16x8 b1 = *(const s16x8*)(pb + rbase + ((g8 * 2 + 64) ^ sw));
      acc[nb] = __builtin_amdgcn_mfma_f32_16x16x32_bf16(af0, b0, acc[nb], 0, 0, 0);
      acc[nb] = __builtin_amdgcn_mfma_f32_16x16x32_bf16(af1, b1, acc[nb], 0, 0, 0);
    }
  };

  for (int tl = 0; tl < NTL; tl += 2) {
    // ---- even tile tl: compute from buf0; stage tl+1 -> buf1 ----
    {
      const size_t tn = (size_t)(tl + 1) * BK;       // tl+1 < NTL always
#pragma unroll
      for (int q = 0; q < 4; ++q)
        sv[q] = *(const s16x8*)(bsrc + goff[q] + tn);
      s16x8 af0, af1;
      scores(tl, af0, af1);
#pragma unroll
      for (int q = 0; q < 4; ++q)
        *(s16x8*)((char*)&Bl[1][0] + ldsoff[q]) = sv[q];
      mfma_tile((const char*)&Bl[0][0], af0, af1);
    }
    __syncthreads();
    // ---- odd tile tl+1: compute from buf1; stage tl+2 -> buf0 ----
    {
      const size_t tn = (size_t)(tl + 2 < NTL ? tl + 2 : tl) * BK;  // clamp
#pragma unroll
      for (int q = 0; q < 4; ++q)
        sv[q] = *(const s16x8*)(bsrc + goff[q] + tn);
      s16x8 af0, af1;
      scores(tl + 1, af0, af1);
#pragma unroll
      for (int q = 0; q < 4; ++q)
        *(s16x8*)((char*)&Bl[0][0] + ldsoff[q]) = sv[q];
      mfma_tile((const char*)&Bl[1][0], af0, af1);
    }
    __syncthreads();
  }

  // row-sums: lanes {l, l^16, l^32, l^48} hold the row's k-slot partials
  lsum += __shfl_xor(lsum, 16);
  lsum += __shfl_xor(lsum, 32);
  if (l < 16) lP[(size_t)s * N + row] = lsum;
  // partial accumulator (C layout: row=(l>>4)*4+rg, col=l&15)
  float* op = accP + (size_t)s * N * F;
#pragma unroll
  for (int nb = 0; nb < 8; ++nb) {
#pragma unroll
    for (int rg = 0; rg < 4; ++rg) {
      int r = i0 + w * BRW + (l >> 4) * 4 + rg;
      op[(size_t)r * F + nb * 16 + r16] = acc[nb][rg];
    }
  }
}

// ---------------------------------------------------------------------------
// K3: combine partials: out = elu( (sum_s accP) / (sum_s lP) )
// ---------------------------------------------------------------------------
template <int KS>
__global__ __launch_bounds__(256) void k_comb(
    const float* __restrict__ accP, const float* __restrict__ lP,
    float* __restrict__ out) {
  const int idx = blockIdx.x * 256 + threadIdx.x;  // one f32x4 per thread
  const int i   = idx >> 5;                        // row (F/4 = 32 per row)
  f32x4 v = {};
  float lt = 0.f;
#pragma unroll
  for (int s = 0; s < KS; ++s) {
    v += *(const f32x4*)(accP + (size_t)s * N * F + (size_t)idx * 4);
    lt += lP[(size_t)s * N + i];
  }
  f32x4 o;
#pragma unroll
  for (int u = 0; u < 4; ++u) {
    float x = v[u] / lt;
    o[u] = x > 0.f ? x : __expf(x) - 1.f;          // ELU
  }
  *(f32x4*)(out + (size_t)idx * 4) = o;
}

// ---------------------------------------------------------------------------
extern "C" void kernel_launch(void* const* d_in, const int* in_sizes, int n_in,
                              void* d_out, int out_size, void* d_ws, size_t ws_size,
                              hipStream_t stream) {
  const float* h   = (const float*)d_in[0];
  const int*   adj = (const int*)d_in[1];
  const float* w   = (const float*)d_in[2];
  const float* a   = (const float*)d_in[3];
  float* out = (float*)d_out;

  // ws: WhbT bf16 [F][N] | Wh1 [N] | Wh2 [N] | lP [KS][N] | accP [KS][N][F]
  char* ws = (char*)d_ws;
  __hip_bfloat16* WhbT = (__hip_bfloat16*)ws;
  float* Wh1 = (float*)(ws + (size_t)F * N * 2);
  float* Wh2 = Wh1 + N;
  float* lP  = Wh2 + N;

  const size_t fixed = (size_t)F * N * 2 + 2 * (size_t)N * 4;
  const size_t need8 = fixed + 8 * (size_t)N * 4 + 8 * (size_t)N * F * 4;

  k_wh<<<N / 32, 256, 0, stream>>>(h, w, a, WhbT, Wh1, Wh2);
  if (ws_size >= need8) {
    constexpr int KS = 8;
    float* accP = lP + (size_t)KS * N;
    k_attn<KS><<<dim3(N / BR, KS), 256, 0, stream>>>(adj, Wh1, Wh2, WhbT,
                                                     accP, lP);
    k_comb<KS><<<(N * F / 4) / 256, 256, 0, stream>>>(accP, lP, out);
  } else {
    constexpr int KS = 4;
    float* accP = lP + (size_t)KS * N;
    k_attn<KS><<<dim3(N / BR, KS), 256, 0, stream>>>(adj, Wh1, Wh2, WhbT,
                                                     accP, lP);
    k_comb<KS><<<(N * F / 4) / 256, 256, 0, stream>>>(accP, lP, out);
  }
}